// Round 11
// baseline (113.539 us; speedup 1.0000x reference)
//
#include <hip/hip_runtime.h>
#include <hip/hip_fp16.h>

typedef _Float16 f16x8 __attribute__((ext_vector_type(8)));
typedef _Float16 f16x4 __attribute__((ext_vector_type(4)));
typedef float f32x4 __attribute__((ext_vector_type(4)));

// Workspace layout (bytes):
//   qv     [0,       65536)   : 32x512 f32   q = query @ Wq^T
//   bfrag  [65536,   589824)  : 512x512 f16  Wk^T in MFMA-fragment-major layout
//   scores [589824,  851968)  : 32x2048 f32  pre-softmax scores
//   vpart  [851968,  1900544) : 1024x512 f16 per-(b,sc) normalized attn@keys
#define WS_QV 0
#define WS_BF 65536
#define WS_SC 589824
#define WS_VP 851968

#define GLOAD_LDS16(g, l)                                              \
  __builtin_amdgcn_global_load_lds(                                    \
      (const __attribute__((address_space(1))) void*)(g),              \
      (__attribute__((address_space(3))) void*)(l), 16, 0, 0)

// ---------------- P: qv = query@Wq^T (fp32) + prepack Wk -> fp16 fragment layout ----
__global__ __launch_bounds__(256) void prep_kernel(
    const float* __restrict__ query, const float* __restrict__ Wq,
    const float* __restrict__ Wk, float* __restrict__ qv,
    _Float16* __restrict__ bfrag) {
  const int blk = blockIdx.x, tid = threadIdx.x;
  if (blk < 64) {
    const int b = blk >> 1;
    const int h = ((blk & 1) << 8) + tid;
    const float4* qr = (const float4*)(query + (size_t)b * 512);
    const float4* wr = (const float4*)(Wq + (size_t)h * 512);
    float acc = 0.f;
#pragma unroll 8
    for (int i = 0; i < 128; ++i) {
      float4 a = qr[i], w = wr[i];
      acc += a.x * w.x + a.y * w.y + a.z * w.z + a.w * w.w;
    }
    qv[b * 512 + h] = acc;
  } else {
    // B-fragment for mfma_f32_16x16x32_f16: unit u = nt*16 + ks (ks = K-tile, BK=32)
    // lane l supplies B[k = 32*ks + 8*(l>>4)+e][col = 16*nt + (l&15)] = Wk[col][k]
    const int u = (blk - 64) * 4 + (tid >> 6);
    const int l = tid & 63;
    const int col = ((u >> 4) << 4) + (l & 15);
    const int k0 = ((u & 15) << 5) + ((l >> 4) << 3);
    const float4* src = (const float4*)(Wk + (size_t)col * 512 + k0);
    float4 x = src[0], y = src[1];
    f16x8 v;
    v[0] = (_Float16)x.x; v[1] = (_Float16)x.y;
    v[2] = (_Float16)x.z; v[3] = (_Float16)x.w;
    v[4] = (_Float16)y.x; v[5] = (_Float16)y.y;
    v[6] = (_Float16)y.z; v[7] = (_Float16)y.w;
    *(f16x8*)(bfrag + (size_t)u * 512 + l * 8) = v;
  }
}

// ---------------- G: scores GEMM, 8-phase-template port ----------------------------
// Grid 512 (XCD-swizzled); 512 thr / 8 waves (2wm x 4wn); block 128r x 512h; BK=32.
// A: keys fp32, ring-3 x 16KB via glds (pre-swizzled source = T2), cvt at read.
// B: bfrag fp16 units, dbuf x 32KB via glds (lane-linear, conflict-free).
// Per K-tile: 2 phases {ds-reads + glds issues -> s_barrier -> lgkmcnt(0) ->
// setprio(1) 16 MFMA setprio(0)}; counted s_waitcnt vmcnt(2) ONCE per tile
// (A(kt+2) stays in flight); lgkm(0) before each closing barrier = race-free handoff.
__global__ __launch_bounds__(512) void gemm_kernel(
    const float* __restrict__ keys, const _Float16* __restrict__ bfrag,
    const float* __restrict__ qv, const float* __restrict__ w_att,
    float* __restrict__ scores) {
  __shared__ __align__(128) unsigned char Ar[3][16384];  // 128r x 32k fp32
  __shared__ __align__(128) unsigned char Bd[2][32768];  // 32 units x 1KB
  __shared__ float sred[512];                            // 4 wn x 128 rows
  const int tid = threadIdx.x, w = tid >> 6, l = tid & 63;
  const int swz = ((blockIdx.x & 7) << 6) + (blockIdx.x >> 3);
  const int row0 = swz * 128;
  const int b = row0 >> 11;
  const int wm = w >> 2, wn = w & 3;

  // A staging: round j in {0,1}: row r = j*64 + (tid>>3), 16B slot s = tid&7;
  // source pre-swizzled (s ^ (r&7)) so linear glds dest = swizzled layout.
  const int ar_ = tid >> 3, as_ = tid & 7;
  const char* agb = (const char*)keys;
  const size_t asrc0 = (size_t)(row0 + ar_) * 2048 + ((as_ ^ (ar_ & 7)) << 4);
  // B staging: round j in {0..3}: unit uu = j*8 + (tid>>6), lane bytes (tid&63)*16.
  const char* bgb = (const char*)bfrag;
  const int buu = tid >> 6;
  const int bl16 = (tid & 63) << 4;

#define ASTAGE(KT2)                                                            \
  {                                                                            \
    unsigned char* d = Ar[(KT2) % 3];                                          \
    GLOAD_LDS16(agb + asrc0 + (KT2) * 128, d + tid * 16);                      \
    GLOAD_LDS16(agb + asrc0 + 131072 + (KT2) * 128, d + 8192 + tid * 16);      \
  }
#define BSTAGE2(KT1, J0)                                                       \
  {                                                                            \
    unsigned char* d = Bd[(KT1) & 1];                                          \
    GLOAD_LDS16(bgb + ((size_t)(((J0) * 8 + buu) * 16 + (KT1)) << 10) + bl16,  \
                d + (J0) * 8192 + tid * 16);                                   \
    GLOAD_LDS16(                                                               \
        bgb + ((size_t)((((J0) + 1) * 8 + buu) * 16 + (KT1)) << 10) + bl16,    \
        d + ((J0) + 1) * 8192 + tid * 16);                                     \
  }

  f32x4 acc[4][8] = {};
  const int albase = (l >> 4) << 5;      // fp32 k-slot byte (g*32)

#define AFLOAD(KT, AF)                                                         \
  {                                                                            \
    const unsigned char* bb = Ar[(KT) % 3];                                    \
    _Pragma("unroll") for (int mt = 0; mt < 4; ++mt) {                         \
      const int rr = wm * 64 + mt * 16 + (l & 15);                             \
      const int cb = albase ^ ((rr & 7) << 4);                                 \
      const float4 x = *(const float4*)(bb + rr * 128 + cb);                   \
      const float4 y = *(const float4*)(bb + rr * 128 + (cb ^ 16));            \
      f16x8 h;                                                                 \
      h[0] = (_Float16)x.x; h[1] = (_Float16)x.y;                              \
      h[2] = (_Float16)x.z; h[3] = (_Float16)x.w;                              \
      h[4] = (_Float16)y.x; h[5] = (_Float16)y.y;                              \
      h[6] = (_Float16)y.z; h[7] = (_Float16)y.w;                              \
      AF[mt] = h;                                                              \
    }                                                                          \
  }
#define BFLOAD(KT, P, BF)                                                      \
  {                                                                            \
    const unsigned char* bb = Bd[(KT) & 1];                                    \
    _Pragma("unroll") for (int j = 0; j < 4; ++j)                              \
        BF[j] = *(const f16x8*)(bb + (wn * 8 + (P) * 4 + j) * 1024 + l * 16);  \
  }
#define MM16(AF, BF, P)                                                        \
  {                                                                            \
    __builtin_amdgcn_s_setprio(1);                                             \
    _Pragma("unroll") for (int mt = 0; mt < 4; ++mt)                           \
        _Pragma("unroll") for (int j = 0; j < 4; ++j)                          \
            acc[mt][(P) * 4 + j] = __builtin_amdgcn_mfma_f32_16x16x32_f16(     \
                AF[mt], BF[j], acc[mt][(P) * 4 + j], 0, 0, 0);                 \
    __builtin_amdgcn_s_setprio(0);                                             \
  }

#define TILE(KT, DO_B, DO_A, VMS)                                              \
  {                                                                            \
    f16x8 af[4], bf[4];                                                        \
    AFLOAD(KT, af);                                                            \
    BFLOAD(KT, 0, bf);                                                         \
    if (DO_B) BSTAGE2((KT) + 1, 0);                                            \
    __builtin_amdgcn_sched_barrier(0);                                         \
    __builtin_amdgcn_s_barrier();                                              \
    asm volatile("s_waitcnt lgkmcnt(0)" ::: "memory");                         \
    __builtin_amdgcn_sched_barrier(0);                                         \
    MM16(af, bf, 0);                                                           \
    __builtin_amdgcn_sched_barrier(0);                                         \
    BFLOAD(KT, 1, bf);                                                         \
    if (DO_B) BSTAGE2((KT) + 1, 2);                                            \
    if (DO_A) ASTAGE((KT) + 2);                                                \
    __builtin_amdgcn_sched_barrier(0);                                         \
    __builtin_amdgcn_s_barrier();                                              \
    asm volatile("s_waitcnt lgkmcnt(0)" ::: "memory");                         \
    __builtin_amdgcn_sched_barrier(0);                                         \
    MM16(af, bf, 1);                                                           \
    __builtin_amdgcn_sched_barrier(0);                                         \
    asm volatile("s_waitcnt vmcnt(" VMS ")" ::: "memory");                     \
    __builtin_amdgcn_s_barrier();                                              \
  }

  // ---- prologue: A(0), B(0), A(1) issued; wait all but A(1)'s 2
  ASTAGE(0);
  BSTAGE2(0, 0); BSTAGE2(0, 2);
  ASTAGE(1);
  __builtin_amdgcn_sched_barrier(0);
  asm volatile("s_waitcnt vmcnt(2)" ::: "memory");
  __builtin_amdgcn_s_barrier();

  TILE(0, 1, 1, "2")  TILE(1, 1, 1, "2")  TILE(2, 1, 1, "2")  TILE(3, 1, 1, "2")
  TILE(4, 1, 1, "2")  TILE(5, 1, 1, "2")  TILE(6, 1, 1, "2")  TILE(7, 1, 1, "2")
  TILE(8, 1, 1, "2")  TILE(9, 1, 1, "2")  TILE(10, 1, 1, "2") TILE(11, 1, 1, "2")
  TILE(12, 1, 1, "2") TILE(13, 1, 1, "2") TILE(14, 1, 0, "0") TILE(15, 0, 0, "0")

  // ---- epilogue: tanh(qv + k) * w_att over this wave's 128 h, 64 rows
  float rs[16];
#pragma unroll
  for (int i = 0; i < 16; ++i) rs[i] = 0.f;
#pragma unroll
  for (int nt = 0; nt < 8; ++nt) {
    const int h = (wn << 7) + (nt << 4) + (l & 15);
    const float q = qv[b * 512 + h];
    const float wa = w_att[h];
#pragma unroll
    for (int mt = 0; mt < 4; ++mt)
#pragma unroll
      for (int r = 0; r < 4; ++r) {
        float x = q + acc[mt][nt][r];
        float e = __expf(x + x);
        float t = 1.f - __fdividef(2.f, e + 1.f);
        rs[mt * 4 + r] = __builtin_fmaf(t, wa, rs[mt * 4 + r]);
      }
  }
#pragma unroll
  for (int st = 1; st <= 8; st <<= 1)
#pragma unroll
    for (int i = 0; i < 16; ++i)
      rs[i] += __shfl_xor(rs[i], st, 64);

  {
    const int idx = l & 15;
    float v = rs[0];
#pragma unroll
    for (int i = 1; i < 16; ++i) v = (idx == i) ? rs[i] : v;
    // local row: mt*16 + (l>>4)*4 + r
    const int rloc = ((idx >> 2) << 4) + ((l >> 4) << 2) + (idx & 3);
    sred[wn * 128 + wm * 64 + rloc] = v;
  }
  __syncthreads();
  if (tid < 128) {
    float s = sred[tid] + sred[128 + tid] + sred[256 + tid] + sred[384 + tid];
    scores[row0 + tid] = s;
  }
}

// ---------------- S: global softmax + attn + normalized V-partial ------------------
// Grid 1024 = (b, sc): softmax over full row, V over 64-row chunk.
__global__ __launch_bounds__(256) void softv_kernel(
    const float* __restrict__ keys, const float* __restrict__ scores,
    float* __restrict__ attn, _Float16* __restrict__ vpart) {
  __shared__ float pe[2048];
  __shared__ float red_mx[4], red_se[4];
  __shared__ float4 comb[128];
  const int tid = threadIdx.x;
  const int b = blockIdx.x >> 5, sc = blockIdx.x & 31;
  const float* srow = scores + (size_t)b * 2048;

  float sv[8];
  float mx = -1e30f;
#pragma unroll
  for (int i = 0; i < 8; ++i) {
    sv[i] = srow[i * 256 + tid];
    mx = fmaxf(mx, sv[i]);
  }
#pragma unroll
  for (int st = 32; st >= 1; st >>= 1) mx = fmaxf(mx, __shfl_xor(mx, st, 64));
  if ((tid & 63) == 0) red_mx[tid >> 6] = mx;
  __syncthreads();
  mx = fmaxf(fmaxf(red_mx[0], red_mx[1]), fmaxf(red_mx[2], red_mx[3]));

  float se = 0.f;
#pragma unroll
  for (int i = 0; i < 8; ++i) {
    float e = __expf(sv[i] - mx);
    pe[i * 256 + tid] = e;
    se += e;
  }
#pragma unroll
  for (int st = 32; st >= 1; st >>= 1) se += __shfl_xor(se, st, 64);
  if ((tid & 63) == 0) red_se[tid >> 6] = se;
  __syncthreads();     // pe[] complete + red_se visible
  se = red_se[0] + red_se[1] + red_se[2] + red_se[3];
  const float rinv = 1.f / se;

  if (tid < 64) {
    int s = sc * 64 + tid;
    attn[(size_t)b * 2048 + s] = pe[s] * rinv;
  }

  // V: thread (c4, rg): float4 col c4, rows rg*32..+32 of this chunk
  const int c4 = tid & 127, rg = tid >> 7;
  const float4* kb = (const float4*)(keys + ((size_t)(b * 2048 + sc * 64 + rg * 32)) * 512);
  float4 a; a.x = 0.f; a.y = 0.f; a.z = 0.f; a.w = 0.f;
#pragma unroll 4
  for (int i = 0; i < 32; ++i) {
    float p = pe[sc * 64 + rg * 32 + i];
    float4 kv = kb[(size_t)i * 128 + c4];
    a.x = __builtin_fmaf(p, kv.x, a.x);
    a.y = __builtin_fmaf(p, kv.y, a.y);
    a.z = __builtin_fmaf(p, kv.z, a.z);
    a.w = __builtin_fmaf(p, kv.w, a.w);
  }
  if (rg) comb[c4] = a;
  __syncthreads();
  if (!rg) {
    float4 o = comb[c4];
    f16x4 h;
    h[0] = (_Float16)((a.x + o.x) * rinv);
    h[1] = (_Float16)((a.y + o.y) * rinv);
    h[2] = (_Float16)((a.z + o.z) * rinv);
    h[3] = (_Float16)((a.w + o.w) * rinv);
    *(f16x4*)(vpart + (size_t)blockIdx.x * 512 + c4 * 4) = h;
  }
}

// ---------------- R: reduce 32 chunk-partials -> out -------------------------------
__global__ __launch_bounds__(256) void reduce_kernel(
    const _Float16* __restrict__ vpart, float* __restrict__ out) {
  const int t = blockIdx.x * 256 + threadIdx.x;   // 16384 outputs
  const int b = t >> 9, d = t & 511;
  float s = 0.f;
#pragma unroll
  for (int sc = 0; sc < 32; ++sc)
    s += (float)vpart[((size_t)(b * 32 + sc)) * 512 + d];
  out[t] = s;
}

extern "C" void kernel_launch(void* const* d_in, const int* in_sizes, int n_in,
                              void* d_out, int out_size, void* d_ws, size_t ws_size,
                              hipStream_t stream) {
  const float* query = (const float*)d_in[0];
  const float* keys  = (const float*)d_in[1];
  const float* Wq    = (const float*)d_in[2];
  const float* Wk    = (const float*)d_in[3];
  const float* w_att = (const float*)d_in[4];
  float* out  = (float*)d_out;                  // [32,512]
  float* attn = out + 16384;                    // [32,2048]
  char* ws = (char*)d_ws;
  float*    qv     = (float*)(ws + WS_QV);
  _Float16* bfrag  = (_Float16*)(ws + WS_BF);
  float*    scores = (float*)(ws + WS_SC);
  _Float16* vpart  = (_Float16*)(ws + WS_VP);

  prep_kernel<<<192, 256, 0, stream>>>(query, Wq, Wk, qv, bfrag);
  gemm_kernel<<<512, 512, 0, stream>>>(keys, bfrag, qv, w_att, scores);
  softv_kernel<<<1024, 256, 0, stream>>>(keys, scores, attn, vpart);
  reduce_kernel<<<64, 256, 0, stream>>>(vpart, out);
}